// Round 7
// baseline (231.492 us; speedup 1.0000x reference)
//
#include <hip/hip_runtime.h>
#include <math.h>
#include <stdint.h>

typedef unsigned short u16;
typedef __attribute__((ext_vector_type(8))) short short8;
typedef __attribute__((ext_vector_type(4))) float f32x4;

// gate scale: 0.125 (attn scale) * log2(e)  -> p = exp2(s * gate)
#define GATE_SCALE 0.18033688011112042f

#if __has_builtin(__builtin_amdgcn_exp2f)
#define FEXP2(x) __builtin_amdgcn_exp2f(x)
#else
#define FEXP2(x) exp2f(x)
#endif

// fp32 -> bf16 round-to-nearest-even
__device__ __forceinline__ u16 f2b(float f) {
    union { float f; unsigned u; } v; v.f = f;
    unsigned r = v.u + 0x7fffu + ((v.u >> 16) & 1u);
    return (u16)(r >> 16);
}
// fp32 -> bf16 round-half-up
__device__ __forceinline__ u16 f2b_hu(float f) {
    union { float f; unsigned u; } v; v.f = f;
    return (u16)((v.u + 0x8000u) >> 16);
}
__device__ __forceinline__ float b2f(u16 u) {
    union { float f; unsigned u; } v; v.u = ((unsigned)u) << 16; return v.f;
}

// async global->LDS, 16B per lane. lds base wave-uniform; HW adds lane*16.
#define GLL16(gsrc, ldsbase) __builtin_amdgcn_global_load_lds(                    \
    (__attribute__((address_space(1))) void*)(uintptr_t)(gsrc),                   \
    (__attribute__((address_space(3))) void*)(uint32_t)(uintptr_t)(ldsbase),      \
    16, 0, 0)

// ---------------------------------------------------------------------------
// K0: merged prep. Blocks [0,3072): gate = bf16(GATE_SCALE*sigmoid(mask)),
// permuted for the SWAPPED-S layout (R11): slot i*4+nt at lane (w,l) holds
// gate[q = 16w+fr][k = 16nt+4fq+i]  (was gate[16w+4fq+i][nt*16+fr]).
// Blocks [3072, 11520): convert x / w_qkv / w_proj to bf16.
// ---------------------------------------------------------------------------
#define NX4  1572864   // 6291456/4
#define NW14 442368
#define NW24 147456
#define NXW4 (NX4 + NW14 + NW24)   // 2162688

__global__ __launch_bounds__(256) void prep_all(
    const float4* __restrict__ x, const float4* __restrict__ wq,
    const float4* __restrict__ wp,
    ushort4* __restrict__ xb, ushort4* __restrict__ wqb,
    ushort4* __restrict__ wpb,
    const float4* __restrict__ mask4, u16* __restrict__ gp)
{
    __shared__ u16 L[64][72];                   // +8 u16 pad (gate path only)
    const int bx = blockIdx.x;
    const int t = threadIdx.x;

    if (bx >= 3072) {                           // ---- xw convert path ----
        size_t i = (size_t)(bx - 3072) * 256 + t;
        float4 v; ushort4* dst; size_t j;
        if (i < NX4)            { j = i;               v = x[j];  dst = xb;  }
        else if (i < NX4 + NW14){ j = i - NX4;         v = wq[j]; dst = wqb; }
        else                    { j = i - (NX4 + NW14);v = wp[j]; dst = wpb; }
        ushort4 o; o.x = f2b(v.x); o.y = f2b(v.y); o.z = f2b(v.z); o.w = f2b(v.w);
        dst[j] = o;
        return;
    }

    // ---- gate path ----
    const int bid = bx;                         // h*256 + qt*16 + kt
    const int kt = bid & 15, qt = (bid >> 4) & 15, h = bid >> 8;

    #pragma unroll
    for (int s = 0; s < 4; ++s) {
        const int idx = t + s * 256;            // 0..1023
        const int row = idx >> 4, c4 = idx & 15;
        float4 v = mask4[(size_t)(h * 1024 + qt * 64 + row) * 256 + kt * 16 + c4];
        L[row][c4 * 4 + 0] = f2b(GATE_SCALE / (1.f + __expf(-v.x)));
        L[row][c4 * 4 + 1] = f2b(GATE_SCALE / (1.f + __expf(-v.y)));
        L[row][c4 * 4 + 2] = f2b(GATE_SCALE / (1.f + __expf(-v.z)));
        L[row][c4 * 4 + 3] = f2b(GATE_SCALE / (1.f + __expf(-v.w)));
    }
    __syncthreads();

    const int w = t >> 6, l = t & 63;
    const int fq = l >> 4, fr = l & 15;
    union { u16 u[16]; float4 f[2]; } vals;
    #pragma unroll
    for (int i = 0; i < 4; ++i)
        #pragma unroll
        for (int nt = 0; nt < 4; ++nt)
            vals.u[i * 4 + nt] = L[16 * w + fr][nt * 16 + 4 * fq + i];
    float4* dst = (float4*)(gp + (size_t)bid * 4096 + (size_t)t * 16);
    dst[0] = vals.f[0];
    dst[1] = vals.f[1];
}

// ---------------------------------------------------------------------------
// K1: QKV GEMM. R9-verified (51.0 us): block tile 128x256, 4 waves, per-wave
// 128x64 (acc[8][4]), depth-3 counted-vmcnt(6) pipeline, conflict-free
// swizzles, XCD-chunked grid 576 (72/XCD), __launch_bounds__(256,2).
// q/k written (B,H,N,64); V written TRANSPOSED (B,H,64,N).
// ---------------------------------------------------------------------------
__global__ __launch_bounds__(256, 2) void qkv_gemm(
    const u16* __restrict__ xb, const u16* __restrict__ wb,
    u16* __restrict__ qb, u16* __restrict__ kb, u16* __restrict__ vb)
{
    __shared__ u16 As[3][4096];     // 128 rows x 32 k
    __shared__ u16 Bs[3][8192];     // 256 rows x 32 k
    const int t = threadIdx.x, l = t & 63, w = t >> 6;
    const int wc = w * 64;          // per-wave N-slice; all waves share M 0..127

    // XCD-chunked bijective remap: 576 blocks, 72 per XCD
    const int orig = blockIdx.x;
    const int nid = (orig & 7) * 72 + (orig >> 3);
    const int m0 = (nid / 9) * 128, c0 = (nid % 9) * 256;

    f32x4 acc[8][4];
    #pragma unroll
    for (int i = 0; i < 8; ++i)
        #pragma unroll
        for (int j = 0; j < 4; ++j) { f32x4 z = {0.f,0.f,0.f,0.f}; acc[i][j] = z; }

    const int srow = l >> 2, sseg = l & 3;
    const int gcol = ((sseg ^ ((srow >> 1) & 3)) << 3);
    const u16* aA = xb + (size_t)(m0 + w * 16 + srow) * 768 + gcol;
    const u16* aB = wb + (size_t)(c0 + w * 16 + srow) * 768 + gcol;

    const int fr = l & 15, fq = l >> 4;
    const int fseg = (fq ^ ((fr >> 1) & 3)) << 3;

    // per stage: A = 8 wave-loads (2/wave), B = 16 wave-loads (4/wave)
    auto stage = [&](int bi, int koff) {
        GLL16(aA + koff,                      &As[bi][(w + 0) * 512]);
        GLL16(aA + koff + (size_t)64 * 768,   &As[bi][(w + 4) * 512]);
        GLL16(aB + koff,                      &Bs[bi][(w + 0) * 512]);
        GLL16(aB + koff + (size_t)64 * 768,   &Bs[bi][(w + 4) * 512]);
        GLL16(aB + koff + (size_t)128 * 768,  &Bs[bi][(w + 8) * 512]);
        GLL16(aB + koff + (size_t)192 * 768,  &Bs[bi][(w + 12) * 512]);
    };

    stage(0, 0);        // kt=0
    stage(1, 32);       // kt=1

    int cur = 0;
    for (int kt = 0; kt < 24; ++kt) {
        if (kt < 23) asm volatile("s_waitcnt vmcnt(6)" ::: "memory");
        else         asm volatile("s_waitcnt vmcnt(0)" ::: "memory");
        __builtin_amdgcn_s_barrier();
        if (kt < 22) {
            const int nn = (cur == 0) ? 2 : cur - 1;   // (cur+2)%3
            stage(nn, (kt + 2) * 32);
        }
        const u16* A = As[cur];
        const u16* B = Bs[cur];
        short8 af[8], bf[4];
        #pragma unroll
        for (int mt = 0; mt < 8; ++mt)
            af[mt] = *(const short8*)&A[(mt * 16 + fr) * 32 + fseg];
        #pragma unroll
        for (int nt = 0; nt < 4; ++nt)
            bf[nt] = *(const short8*)&B[(wc + nt * 16 + fr) * 32 + fseg];
        #pragma unroll
        for (int mt = 0; mt < 8; ++mt)
            #pragma unroll
            for (int nt = 0; nt < 4; ++nt)
                acc[mt][nt] = __builtin_amdgcn_mfma_f32_16x16x32_bf16(
                    af[mt], bf[nt], acc[mt][nt], 0, 0, 0);
        cur = (cur == 2) ? 0 : cur + 1;
    }

    const int b = m0 >> 10;
    const int n0 = m0 & 1023;
    #pragma unroll
    for (int nt = 0; nt < 4; ++nt) {
        const int c = c0 + wc + nt * 16 + fr;
        const int which = c / 768;
        const int rem = c - which * 768;
        const int h = rem >> 6, d = rem & 63;
        if (which < 2) {
            u16* dst = ((which == 0) ? qb : kb)
                       + ((size_t)(b * 12 + h) * 1024) * 64 + d;
            #pragma unroll
            for (int mt = 0; mt < 8; ++mt)
                #pragma unroll
                for (int r = 0; r < 4; ++r) {
                    const int n = n0 + mt * 16 + fq * 4 + r;
                    dst[(size_t)n * 64] = f2b(acc[mt][nt][r]);
                }
        } else {
            u16* dst = vb + ((size_t)(b * 12 + h) * 64 + d) * 1024
                          + n0 + fq * 4;
            #pragma unroll
            for (int mt = 0; mt < 8; ++mt) {
                ushort4 pk;
                pk.x = f2b(acc[mt][nt][0]); pk.y = f2b(acc[mt][nt][1]);
                pk.z = f2b(acc[mt][nt][2]); pk.w = f2b(acc[mt][nt][3]);
                *(ushort4*)(dst + mt * 16) = pk;
            }
        }
    }
}

// ---------------------------------------------------------------------------
// K2: flash attention. R11 = R10 + swapped-QK packed-P path:
//  * S^T = mfma(K, Q): lane holds P[q=16w+fr, k=16nt+4fq+{0..3}] -- 4
//    CONSECUTIVE k -> pack via 2x v_cvt_pk_bf16_f32, write ONE ds_write_b64
//    per (qh,nt): 8 b64 writes/wave/kt vs 32 b16 writes (LDS pipe was the
//    top consumer: ~63% busy; 32 scalar writes + pack VALU dominated).
//  * Write slot swizzle slot=(4nt+fq)^(2*(fr&7)): derived so the existing
//    sega/segb b128 read addresses remain bit-exact valid (even key keeps
//    16B pair order; byte = row*128 + 8*slot).
//  * l-accumulator: one scalar/lane (sum over its 16 k), reduced with 2
//    shfl_xor(16/32) + 4 shfl redistribution (was 32 shfl_xor).
// PV step, O layout, epilogue writes unchanged. XCD colocating remap +
// setprio kept (R10-verified).
// ---------------------------------------------------------------------------
__global__ __launch_bounds__(256, 3) void flash_attn(
    const u16* __restrict__ qb, const u16* __restrict__ kb,
    const u16* __restrict__ vt, const u16* __restrict__ gperm,
    u16* __restrict__ aob)
{
    __shared__ u16 Ks[2][4096], Vts[2][4096], Ps[4096];
    const int t = threadIdx.x, l = t & 63, w = t >> 6;
    const int bid = blockIdx.x;
    // K/V-colocating remap: all 8 qtb-siblings of one (b,h) on one XCD
    const int xcd = bid & 7, jj = bid >> 3;
    const int bh = (jj % 12) * 8 + xcd;
    const int qtb = jj / 12;
    const int h = bh % 12, b = bh / 12;
    const int q0 = qtb * 128;

    const u16* hq = qb + (size_t)bh * 65536;
    const u16* hk = kb + (size_t)bh * 65536;
    const u16* hv = vt + (size_t)bh * 65536;
    // gate tiles (h, 2*qtb + qh, kt); qh=1 at +16 tiles = +65536 u16
    const u16* hgb = gperm + ((size_t)h * 256 + qtb * 32) * 4096 + (w * 64 + l) * 16;

    const int sr = l >> 3, ss = l & 7;
    const int sg = ((ss ^ (sr & 7)) << 3);
    const int j0 = w * 2, j1 = j0 + 1;

    const int fq = l >> 4, fr = l & 15;
    const int sega = ((fq ^ (fr & 7)) << 3);
    const int segb = (((4 + fq) ^ (fr & 7)) << 3);

    // Q A-frags (kt-invariant) direct from global
    short8 aq[2][2];
    #pragma unroll
    for (int qh = 0; qh < 2; ++qh) {
        const u16* qrow = hq + (size_t)(q0 + qh * 64 + 16 * w + fr) * 64;
        aq[qh][0] = *(const short8*)(qrow + fq * 8);
        aq[qh][1] = *(const short8*)(qrow + 32 + fq * 8);
    }

    // stage kt=0 K/V into buf 0
    GLL16(hk + (size_t)(j0 * 8 + sr) * 64 + sg, &Ks[0][j0 * 512]);
    GLL16(hk + (size_t)(j1 * 8 + sr) * 64 + sg, &Ks[0][j1 * 512]);
    GLL16(hv + (size_t)(j0 * 8 + sr) * 1024 + sg, &Vts[0][j0 * 512]);
    GLL16(hv + (size_t)(j1 * 8 + sr) * 1024 + sg, &Vts[0][j1 * 512]);
    __builtin_amdgcn_sched_barrier(0);

    // gate prefetch for kt=0 (both halves)
    short8 gn[4];
    gn[0] = *(const short8*)(hgb);
    gn[1] = *(const short8*)(hgb + 8);
    gn[2] = *(const short8*)(hgb + 65536);
    gn[3] = *(const short8*)(hgb + 65536 + 8);

    float l_sum[2] = {0.f, 0.f};
    f32x4 o[2][4];
    #pragma unroll
    for (int qh = 0; qh < 2; ++qh)
        #pragma unroll
        for (int nt = 0; nt < 4; ++nt) { f32x4 z = {0.f,0.f,0.f,0.f}; o[qh][nt] = z; }

    for (int kt = 0; kt < 16; ++kt) {
        // own buf[kt&1] GLL16s done (4 gate loads may stay outstanding)
        asm volatile("s_waitcnt vmcnt(4)" ::: "memory");
        __builtin_amdgcn_s_barrier();

        if (kt < 15) {                          // stage kt+1 into buf^1
            const size_t ko = (size_t)(kt + 1) * 64;
            u16* kd = &Ks[(kt + 1) & 1][0];
            u16* vd = &Vts[(kt + 1) & 1][0];
            GLL16(hk + (ko + j0 * 8 + sr) * 64 + sg, kd + j0 * 512);
            GLL16(hk + (ko + j1 * 8 + sr) * 64 + sg, kd + j1 * 512);
            GLL16(hv + (size_t)(j0 * 8 + sr) * 1024 + ko + sg, vd + j0 * 512);
            GLL16(hv + (size_t)(j1 * 8 + sr) * 1024 + ko + sg, vd + j1 * 512);
            __builtin_amdgcn_sched_barrier(0);  // keep GLL16s older than gate loads
        }

        short8 g[4];
        #pragma unroll
        for (int s = 0; s < 4; ++s) g[s] = gn[s];
        if (kt < 15) {                          // gate register prefetch, 1 ahead
            const size_t go = (size_t)(kt + 1) * 4096;
            gn[0] = *(const short8*)(hgb + go);
            gn[1] = *(const short8*)(hgb + go + 8);
            gn[2] = *(const short8*)(hgb + 65536 + go);
            gn[3] = *(const short8*)(hgb + 65536 + go + 8);
        }

        const u16* KS = &Ks[kt & 1][0];
        const u16* VS = &Vts[kt & 1][0];

        // S^T = K . Q^T (swapped): lane (fq,fr) reg i of tile nt holds
        // S[k = 16nt+4fq+i, q = 16w+fr]. k-frags read once, used twice.
        f32x4 sv[2][4];
        __builtin_amdgcn_s_setprio(1);
        #pragma unroll
        for (int nt = 0; nt < 4; ++nt) {
            short8 kf0 = *(const short8*)&KS[(nt * 16 + fr) * 64 + sega];
            short8 kf1 = *(const short8*)&KS[(nt * 16 + fr) * 64 + segb];
            f32x4 z0 = {0.f,0.f,0.f,0.f};
            z0 = __builtin_amdgcn_mfma_f32_16x16x32_bf16(kf0, aq[0][0], z0, 0, 0, 0);
            z0 = __builtin_amdgcn_mfma_f32_16x16x32_bf16(kf1, aq[0][1], z0, 0, 0, 0);
            sv[0][nt] = z0;
            f32x4 z1 = {0.f,0.f,0.f,0.f};
            z1 = __builtin_amdgcn_mfma_f32_16x16x32_bf16(kf0, aq[1][0], z1, 0, 0, 0);
            z1 = __builtin_amdgcn_mfma_f32_16x16x32_bf16(kf1, aq[1][1], z1, 0, 0, 0);
            sv[1][nt] = z1;
        }
        __builtin_amdgcn_s_setprio(0);

        // gate + exp + packed P->LDS per half; ap frags captured before
        // Ps reuse by the next qh.
        short8 ap[2][2];
        #pragma unroll
        for (int qh = 0; qh < 2; ++qh) {
            #pragma unroll
            for (int nt = 0; nt < 4; ++nt) {
                const float g0 = b2f((u16)g[2 * qh][nt]);
                const float g1 = b2f((u16)g[2 * qh][4 + nt]);
                const float g2 = b2f((u16)g[2 * qh + 1][nt]);
                const float g3 = b2f((u16)g[2 * qh + 1][4 + nt]);
                const float p0 = FEXP2(sv[qh][nt][0] * g0);
                const float p1 = FEXP2(sv[qh][nt][1] * g1);
                const float p2 = FEXP2(sv[qh][nt][2] * g2);
                const float p3 = FEXP2(sv[qh][nt][3] * g3);
                l_sum[qh] += (p0 + p1) + (p2 + p3);
                unsigned lo, hi;
                asm("v_cvt_pk_bf16_f32 %0, %1, %2" : "=v"(lo) : "v"(p0), "v"(p1));
                asm("v_cvt_pk_bf16_f32 %0, %1, %2" : "=v"(hi) : "v"(p2), "v"(p3));
                uint2 pk2; pk2.x = lo; pk2.y = hi;
                *(uint2*)&Ps[w * 1024 + fr * 64
                             + 4 * ((4 * nt + fq) ^ (2 * (fr & 7)))] = pk2;
            }
            ap[qh][0] = *(const short8*)&Ps[w * 1024 + fr * 64 + sega];
            ap[qh][1] = *(const short8*)&Ps[w * 1024 + fr * 64 + segb];
        }

        // O += P . V for both halves; v-frags read once, used twice
        __builtin_amdgcn_s_setprio(1);
        #pragma unroll
        for (int nt = 0; nt < 4; ++nt) {
            short8 vf0 = *(const short8*)&VS[(nt * 16 + fr) * 64 + sega];
            short8 vf1 = *(const short8*)&VS[(nt * 16 + fr) * 64 + segb];
            o[0][nt] = __builtin_amdgcn_mfma_f32_16x16x32_bf16(ap[0][0], vf0, o[0][nt], 0, 0, 0);
            o[0][nt] = __builtin_amdgcn_mfma_f32_16x16x32_bf16(ap[0][1], vf1, o[0][nt], 0, 0, 0);
            o[1][nt] = __builtin_amdgcn_mfma_f32_16x16x32_bf16(ap[1][0], vf0, o[1][nt], 0, 0, 0);
            o[1][nt] = __builtin_amdgcn_mfma_f32_16x16x32_bf16(ap[1][1], vf1, o[1][nt], 0, 0, 0);
        }
        __builtin_amdgcn_s_setprio(0);
    }

    // l reduction: lane holds partial sum for q-row 16w+fr (its 16 k-vals
    // across fq groups) -> xor over fq bits, then redistribute to the
    // O rows (4fq+i) this lane writes.
    #pragma unroll
    for (int qh = 0; qh < 2; ++qh) {
        float s = l_sum[qh];
        s += __shfl_xor(s, 16, 64);
        s += __shfl_xor(s, 32, 64);
        #pragma unroll
        for (int i = 0; i < 4; ++i) {
            const float inv = 1.f / __shfl(s, (fq << 4) | (4 * fq + i), 64);
            const int n = q0 + qh * 64 + 16 * w + 4 * fq + i;
            const size_t rowoff = ((size_t)b * 1024 + n) * 768 + h * 64;
            #pragma unroll
            for (int nt = 0; nt < 4; ++nt)
                aob[rowoff + nt * 16 + fr] = f2b(o[qh][nt][i] * inv);
        }
    }
}

// ---------------------------------------------------------------------------
// K3: output projection. R9-verified: 128x256 block tile, per-wave 128x64
// (acc[8][4]), depth-3 vmcnt(6) pipeline, grid 192 (24/XCD). fp32 out+bias.
// ---------------------------------------------------------------------------
__global__ __launch_bounds__(256, 2) void proj_gemm(
    const u16* __restrict__ aob, const u16* __restrict__ wb,
    const float* __restrict__ bproj, float* __restrict__ out)
{
    __shared__ u16 As[3][4096];
    __shared__ u16 Bs[3][8192];
    const int t = threadIdx.x, l = t & 63, w = t >> 6;
    const int wc = w * 64;

    const int orig = blockIdx.x;                 // 192 blocks
    const int nid = (orig & 7) * 24 + (orig >> 3);
    const int m0 = (nid / 3) * 128, c0 = (nid % 3) * 256;

    f32x4 acc[8][4];
    #pragma unroll
    for (int i = 0; i < 8; ++i)
        #pragma unroll
        for (int j = 0; j < 4; ++j) { f32x4 z = {0.f,0.f,0.f,0.f}; acc[i][j] = z; }

    const int srow = l >> 2, sseg = l & 3;
    const int gcol = ((sseg ^ ((srow >> 1) & 3)) << 3);
    const u16* aA = aob + (size_t)(m0 + w * 16 + srow) * 768 + gcol;
    const u16* aB = wb + (size_t)(c0 + w * 16 + srow) * 768 + gcol;

    const int fr = l & 15, fq = l >> 4;
    const int fseg = (fq ^ ((fr >> 1) & 3)) << 3;

    auto stage = [&](int bi, int koff) {
        GLL16(aA + koff,                      &As[bi][(w + 0) * 512]);
        GLL16(aA + koff + (size_t)64 * 768,   &As[bi][(w + 4) * 512]);
        GLL16(aB + koff,                      &Bs[bi][(w + 0) * 512]);
        GLL16(aB + koff + (size_t)64 * 768,   &Bs[bi][(w + 4) * 512]);
        GLL16(aB + koff + (size_t)128 * 768,  &Bs[bi][(w + 8) * 512]);
        GLL16(aB + koff + (size_t)192 * 768,  &Bs[bi][(w + 12) * 512]);
    };

    stage(0, 0);
    stage(1, 32);

    int cur = 0;
    for (int kt = 0; kt < 24; ++kt) {
        if (kt < 23) asm volatile("s_waitcnt vmcnt(6)" ::: "memory");
        else         asm volatile("s_waitcnt vmcnt(0)" ::: "memory");
        __builtin_amdgcn_s_barrier();
        if (kt < 22) {
            const int nn = (cur == 0) ? 2 : cur - 1;
            stage(nn, (kt + 2) * 32);
        }
        const u16* A = As[cur];
        const u16* B = Bs[cur];
        short8 af[8], bf[4];
        #pragma unroll
        for (int mt = 0; mt < 8; ++mt)
            af[mt] = *(const short8*)&A[(mt * 16 + fr) * 32 + fseg];
        #pragma unroll
        for (int nt = 0; nt < 4; ++nt)
            bf[nt] = *(const short8*)&B[(wc + nt * 16 + fr) * 32 + fseg];
        #pragma unroll
        for (int mt = 0; mt < 8; ++mt)
            #pragma unroll
            for (int nt = 0; nt < 4; ++nt)
                acc[mt][nt] = __builtin_amdgcn_mfma_f32_16x16x32_bf16(
                    af[mt], bf[nt], acc[mt][nt], 0, 0, 0);
        cur = (cur == 2) ? 0 : cur + 1;
    }

    #pragma unroll
    for (int nt = 0; nt < 4; ++nt) {
        const int c = c0 + wc + nt * 16 + fr;
        const float bias = bproj[c];
        #pragma unroll
        for (int mt = 0; mt < 8; ++mt)
            #pragma unroll
            for (int r = 0; r < 4; ++r) {
                const int m = m0 + mt * 16 + fq * 4 + r;
                out[(size_t)m * 768 + c] = acc[mt][nt][r] + bias;
            }
    }
}

// ---------------------------------------------------------------------------
extern "C" void kernel_launch(void* const* d_in, const int* in_sizes, int n_in,
                              void* d_out, int out_size, void* d_ws, size_t ws_size,
                              hipStream_t stream)
{
    const float* x     = (const float*)d_in[0];
    const float* wqkv  = (const float*)d_in[1];
    const float* wproj = (const float*)d_in[2];
    const float* bproj = (const float*)d_in[3];
    const float* mask  = (const float*)d_in[4];
    float* out = (float*)d_out;

    char* ws = (char*)d_ws;
    u16* gperm  = (u16*)(ws);               // 25,165,824 B
    u16* xb     = (u16*)(ws + 25165824);    // 12,582,912 B
    u16* wqkvb  = (u16*)(ws + 37748736);    //  3,538,944 B
    u16* wprojb = (u16*)(ws + 41287680);    //  1,179,648 B
    u16* qb     = (u16*)(ws + 42467328);    // 12,582,912 B
    u16* kb     = (u16*)(ws + 55050240);    // 12,582,912 B
    u16* vb     = (u16*)(ws + 67633152);    // 12,582,912 B (transposed: B,H,64,N)
    u16* aob    = (u16*)(ws + 80216064);    // 12,582,912 B  (total 92.8 MB)

    prep_all<<<3072 + NXW4 / 256, 256, 0, stream>>>(
        (const float4*)x, (const float4*)wqkv, (const float4*)wproj,
        (ushort4*)xb, (ushort4*)wqkvb, (ushort4*)wprojb,
        (const float4*)mask, gperm);

    qkv_gemm<<<576, 256, 0, stream>>>(xb, wqkvb, qb, kb, vb);

    flash_attn<<<768, 256, 0, stream>>>(qb, kb, vb, gperm, aob);

    proj_gemm<<<192, 256, 0, stream>>>(aob, wprojb, bproj, out);
}

// Round 8
// 230.652 us; speedup vs baseline: 1.0036x; 1.0036x over previous
//
#include <hip/hip_runtime.h>
#include <math.h>
#include <stdint.h>

typedef unsigned short u16;
typedef __attribute__((ext_vector_type(8))) short short8;
typedef __attribute__((ext_vector_type(4))) float f32x4;

// gate scale: 0.125 (attn scale) * log2(e)  -> p = exp2(s * gate)
#define GATE_SCALE 0.18033688011112042f

#if __has_builtin(__builtin_amdgcn_exp2f)
#define FEXP2(x) __builtin_amdgcn_exp2f(x)
#else
#define FEXP2(x) exp2f(x)
#endif

// fp32 -> bf16 round-to-nearest-even
__device__ __forceinline__ u16 f2b(float f) {
    union { float f; unsigned u; } v; v.f = f;
    unsigned r = v.u + 0x7fffu + ((v.u >> 16) & 1u);
    return (u16)(r >> 16);
}
// fp32 -> bf16 round-half-up
__device__ __forceinline__ u16 f2b_hu(float f) {
    union { float f; unsigned u; } v; v.f = f;
    return (u16)((v.u + 0x8000u) >> 16);
}
__device__ __forceinline__ float b2f(u16 u) {
    union { float f; unsigned u; } v; v.u = ((unsigned)u) << 16; return v.f;
}

// async global->LDS, 16B per lane. lds base wave-uniform; HW adds lane*16.
#define GLL16(gsrc, ldsbase) __builtin_amdgcn_global_load_lds(                    \
    (__attribute__((address_space(1))) void*)(uintptr_t)(gsrc),                   \
    (__attribute__((address_space(3))) void*)(uint32_t)(uintptr_t)(ldsbase),      \
    16, 0, 0)

// ---------------------------------------------------------------------------
// K0: merged prep (R6-verified). Blocks [0,3072): gate =
// bf16(GATE_SCALE*sigmoid(mask)), permuted into 16x16 MFMA C-fragment order
// (original, non-swapped layout). Blocks [3072, 11520): x/w_qkv/w_proj bf16.
// ---------------------------------------------------------------------------
#define NX4  1572864   // 6291456/4
#define NW14 442368
#define NW24 147456
#define NXW4 (NX4 + NW14 + NW24)   // 2162688

__global__ __launch_bounds__(256) void prep_all(
    const float4* __restrict__ x, const float4* __restrict__ wq,
    const float4* __restrict__ wp,
    ushort4* __restrict__ xb, ushort4* __restrict__ wqb,
    ushort4* __restrict__ wpb,
    const float4* __restrict__ mask4, u16* __restrict__ gp)
{
    __shared__ u16 L[64][72];                   // +8 u16 pad (gate path only)
    const int bx = blockIdx.x;
    const int t = threadIdx.x;

    if (bx >= 3072) {                           // ---- xw convert path ----
        size_t i = (size_t)(bx - 3072) * 256 + t;
        float4 v; ushort4* dst; size_t j;
        if (i < NX4)            { j = i;               v = x[j];  dst = xb;  }
        else if (i < NX4 + NW14){ j = i - NX4;         v = wq[j]; dst = wqb; }
        else                    { j = i - (NX4 + NW14);v = wp[j]; dst = wpb; }
        ushort4 o; o.x = f2b(v.x); o.y = f2b(v.y); o.z = f2b(v.z); o.w = f2b(v.w);
        dst[j] = o;
        return;
    }

    // ---- gate path ----
    const int bid = bx;                         // h*256 + qt*16 + kt
    const int kt = bid & 15, qt = (bid >> 4) & 15, h = bid >> 8;

    #pragma unroll
    for (int s = 0; s < 4; ++s) {
        const int idx = t + s * 256;            // 0..1023
        const int row = idx >> 4, c4 = idx & 15;
        float4 v = mask4[(size_t)(h * 1024 + qt * 64 + row) * 256 + kt * 16 + c4];
        L[row][c4 * 4 + 0] = f2b(GATE_SCALE / (1.f + __expf(-v.x)));
        L[row][c4 * 4 + 1] = f2b(GATE_SCALE / (1.f + __expf(-v.y)));
        L[row][c4 * 4 + 2] = f2b(GATE_SCALE / (1.f + __expf(-v.z)));
        L[row][c4 * 4 + 3] = f2b(GATE_SCALE / (1.f + __expf(-v.w)));
    }
    __syncthreads();

    const int w = t >> 6, l = t & 63;
    const int fq = l >> 4, fr = l & 15;
    union { u16 u[16]; float4 f[2]; } vals;
    #pragma unroll
    for (int i = 0; i < 4; ++i)
        #pragma unroll
        for (int nt = 0; nt < 4; ++nt)
            vals.u[i * 4 + nt] = L[16 * w + 4 * fq + i][nt * 16 + fr];
    float4* dst = (float4*)(gp + (size_t)bid * 4096 + (size_t)t * 16);
    dst[0] = vals.f[0];
    dst[1] = vals.f[1];
}

// ---------------------------------------------------------------------------
// K1: QKV GEMM. R12: 128x128 tile, 4 waves, acc[4][4] (R1-verified fragment
// machinery), but DEPTH-2 double-buffer + minimum-2-phase loop:
//   vmcnt(0); barrier; stage(next); ds_read; MFMA
// vmcnt(0) drains loads issued one full compute-phase earlier (m230 2ph
// pattern). LDS 32 KB -> 5 blocks/CU (was 2 at 72KB): grid 1152 fits ONE
// dispatch round (balance 4.5/5 = 90% vs 56% for 576@2/CU -- Occupancy was
// 12%, the real qkv bottleneck), 20 waves/CU of cross-block overlap.
// q/k written (B,H,N,64); V written TRANSPOSED (B,H,64,N).
// ---------------------------------------------------------------------------
__global__ __launch_bounds__(256) void qkv_gemm(
    const u16* __restrict__ xb, const u16* __restrict__ wb,
    u16* __restrict__ qb, u16* __restrict__ kb, u16* __restrict__ vb)
{
    __shared__ u16 As[2][4096];
    __shared__ u16 Bs[2][4096];
    const int t = threadIdx.x, l = t & 63, w = t >> 6;
    const int wm = (w & 1) * 64, wn = (w >> 1) * 64;

    const int orig = blockIdx.x + 18 * blockIdx.y;   // gridDim = (18, 64)
    const int nid = (orig & 7) * 144 + (orig >> 3);  // 1152 blocks, 144/XCD
    const int m0 = (nid / 18) * 128, c0 = (nid % 18) * 128;

    f32x4 acc[4][4];
    #pragma unroll
    for (int i = 0; i < 4; ++i)
        #pragma unroll
        for (int j = 0; j < 4; ++j) { f32x4 z = {0.f,0.f,0.f,0.f}; acc[i][j] = z; }

    const int srow = l >> 2, sseg = l & 3;
    const int gcol = ((sseg ^ ((srow >> 1) & 3)) << 3);
    const u16* a0 = xb + (size_t)(m0 + w * 16 + srow) * 768 + gcol;
    const u16* a1 = a0 + (size_t)64 * 768;
    const u16* b0p = wb + (size_t)(c0 + w * 16 + srow) * 768 + gcol;
    const u16* b1p = b0p + (size_t)64 * 768;
    const int wofs = w * 512;

    const int fr = l & 15, fq = l >> 4;
    const int fseg = (fq ^ ((fr >> 1) & 3)) << 3;

    auto stage = [&](int bi, int koff) {
        GLL16(a0 + koff, &As[bi][wofs]);
        GLL16(a1 + koff, &As[bi][2048 + wofs]);
        GLL16(b0p + koff, &Bs[bi][wofs]);
        GLL16(b1p + koff, &Bs[bi][2048 + wofs]);
    };

    stage(0, 0);

    for (int kt = 0; kt < 24; ++kt) {
        // own stage(kt) loads landed; barrier publishes them to all waves
        // AND guarantees buf[(kt+1)&1]'s iter-(kt-1) readers are done.
        asm volatile("s_waitcnt vmcnt(0)" ::: "memory");
        __builtin_amdgcn_s_barrier();
        if (kt < 23) stage((kt + 1) & 1, (kt + 1) * 32);
        const u16* A = As[kt & 1];
        const u16* B = Bs[kt & 1];
        short8 af[4], bf[4];
        #pragma unroll
        for (int mt = 0; mt < 4; ++mt)
            af[mt] = *(const short8*)&A[(wm + mt * 16 + fr) * 32 + fseg];
        #pragma unroll
        for (int nt = 0; nt < 4; ++nt)
            bf[nt] = *(const short8*)&B[(wn + nt * 16 + fr) * 32 + fseg];
        #pragma unroll
        for (int mt = 0; mt < 4; ++mt)
            #pragma unroll
            for (int nt = 0; nt < 4; ++nt)
                acc[mt][nt] = __builtin_amdgcn_mfma_f32_16x16x32_bf16(
                    af[mt], bf[nt], acc[mt][nt], 0, 0, 0);
    }

    const int b = m0 >> 10;
    const int n0 = m0 & 1023;
    #pragma unroll
    for (int nt = 0; nt < 4; ++nt) {
        const int c = c0 + wn + nt * 16 + fr;
        const int which = c / 768;
        const int rem = c - which * 768;
        const int h = rem >> 6, d = rem & 63;
        if (which < 2) {
            u16* dst = ((which == 0) ? qb : kb)
                       + ((size_t)(b * 12 + h) * 1024) * 64 + d;
            #pragma unroll
            for (int mt = 0; mt < 4; ++mt)
                #pragma unroll
                for (int r = 0; r < 4; ++r) {
                    const int n = n0 + wm + mt * 16 + fq * 4 + r;
                    dst[(size_t)n * 64] = f2b(acc[mt][nt][r]);
                }
        } else {
            u16* dst = vb + ((size_t)(b * 12 + h) * 64 + d) * 1024
                          + n0 + wm + fq * 4;
            #pragma unroll
            for (int mt = 0; mt < 4; ++mt) {
                ushort4 pk;
                pk.x = f2b(acc[mt][nt][0]); pk.y = f2b(acc[mt][nt][1]);
                pk.z = f2b(acc[mt][nt][2]); pk.w = f2b(acc[mt][nt][3]);
                *(ushort4*)(dst + mt * 16) = pk;
            }
        }
    }
}

// ---------------------------------------------------------------------------
// K2: flash attention. R6-verified version (REVERT of R7's packed-P path,
// which regressed +4.7 us): normal QK order, scalar P writes, Q direct to
// regs, K/V double-buffer with one raw s_barrier + counted vmcnt(4),
// K/V-colocating XCD remap, setprio around MFMA clusters.
// ---------------------------------------------------------------------------
__global__ __launch_bounds__(256, 3) void flash_attn(
    const u16* __restrict__ qb, const u16* __restrict__ kb,
    const u16* __restrict__ vt, const u16* __restrict__ gperm,
    u16* __restrict__ aob)
{
    __shared__ u16 Ks[2][4096], Vts[2][4096], Ps[4096];
    const int t = threadIdx.x, l = t & 63, w = t >> 6;
    const int bid = blockIdx.x;
    // K/V-colocating remap: all 8 qtb-siblings of one (b,h) on one XCD
    const int xcd = bid & 7, jj = bid >> 3;
    const int bh = (jj % 12) * 8 + xcd;
    const int qtb = jj / 12;
    const int h = bh % 12, b = bh / 12;
    const int q0 = qtb * 128;

    const u16* hq = qb + (size_t)bh * 65536;
    const u16* hk = kb + (size_t)bh * 65536;
    const u16* hv = vt + (size_t)bh * 65536;
    // gate tiles (h, 2*qtb + qh, kt); qh=1 at +16 tiles = +65536 u16
    const u16* hgb = gperm + ((size_t)h * 256 + qtb * 32) * 4096 + (w * 64 + l) * 16;

    const int sr = l >> 3, ss = l & 7;
    const int sg = ((ss ^ (sr & 7)) << 3);
    const int j0 = w * 2, j1 = j0 + 1;

    const int fq = l >> 4, fr = l & 15;
    const int sega = ((fq ^ (fr & 7)) << 3);
    const int segb = (((4 + fq) ^ (fr & 7)) << 3);

    // Q A-frags (kt-invariant) direct from global
    short8 aq[2][2];
    #pragma unroll
    for (int qh = 0; qh < 2; ++qh) {
        const u16* qrow = hq + (size_t)(q0 + qh * 64 + 16 * w + fr) * 64;
        aq[qh][0] = *(const short8*)(qrow + fq * 8);
        aq[qh][1] = *(const short8*)(qrow + 32 + fq * 8);
    }

    // stage kt=0 K/V into buf 0
    GLL16(hk + (size_t)(j0 * 8 + sr) * 64 + sg, &Ks[0][j0 * 512]);
    GLL16(hk + (size_t)(j1 * 8 + sr) * 64 + sg, &Ks[0][j1 * 512]);
    GLL16(hv + (size_t)(j0 * 8 + sr) * 1024 + sg, &Vts[0][j0 * 512]);
    GLL16(hv + (size_t)(j1 * 8 + sr) * 1024 + sg, &Vts[0][j1 * 512]);
    __builtin_amdgcn_sched_barrier(0);

    // gate prefetch for kt=0 (both halves)
    short8 gn[4];
    gn[0] = *(const short8*)(hgb);
    gn[1] = *(const short8*)(hgb + 8);
    gn[2] = *(const short8*)(hgb + 65536);
    gn[3] = *(const short8*)(hgb + 65536 + 8);

    float l_part[2][4] = {{0.f,0.f,0.f,0.f},{0.f,0.f,0.f,0.f}};
    f32x4 o[2][4];
    #pragma unroll
    for (int qh = 0; qh < 2; ++qh)
        #pragma unroll
        for (int nt = 0; nt < 4; ++nt) { f32x4 z = {0.f,0.f,0.f,0.f}; o[qh][nt] = z; }

    for (int kt = 0; kt < 16; ++kt) {
        // own buf[kt&1] GLL16s done (4 gate loads may stay outstanding)
        asm volatile("s_waitcnt vmcnt(4)" ::: "memory");
        __builtin_amdgcn_s_barrier();

        if (kt < 15) {                          // stage kt+1 into buf^1
            const size_t ko = (size_t)(kt + 1) * 64;
            u16* kd = &Ks[(kt + 1) & 1][0];
            u16* vd = &Vts[(kt + 1) & 1][0];
            GLL16(hk + (ko + j0 * 8 + sr) * 64 + sg, kd + j0 * 512);
            GLL16(hk + (ko + j1 * 8 + sr) * 64 + sg, kd + j1 * 512);
            GLL16(hv + (size_t)(j0 * 8 + sr) * 1024 + ko + sg, vd + j0 * 512);
            GLL16(hv + (size_t)(j1 * 8 + sr) * 1024 + ko + sg, vd + j1 * 512);
            __builtin_amdgcn_sched_barrier(0);  // keep GLL16s older than gate loads
        }

        short8 g[4];
        #pragma unroll
        for (int s = 0; s < 4; ++s) g[s] = gn[s];
        if (kt < 15) {                          // gate register prefetch, 1 ahead
            const size_t go = (size_t)(kt + 1) * 4096;
            gn[0] = *(const short8*)(hgb + go);
            gn[1] = *(const short8*)(hgb + go + 8);
            gn[2] = *(const short8*)(hgb + 65536 + go);
            gn[3] = *(const short8*)(hgb + 65536 + go + 8);
        }

        const u16* KS = &Ks[kt & 1][0];
        const u16* VS = &Vts[kt & 1][0];

        // S = Q . K^T for both halves; k-frags read once, used twice
        f32x4 sv[2][4];
        __builtin_amdgcn_s_setprio(1);
        #pragma unroll
        for (int nt = 0; nt < 4; ++nt) {
            short8 kf0 = *(const short8*)&KS[(nt * 16 + fr) * 64 + sega];
            short8 kf1 = *(const short8*)&KS[(nt * 16 + fr) * 64 + segb];
            f32x4 z0 = {0.f,0.f,0.f,0.f};
            z0 = __builtin_amdgcn_mfma_f32_16x16x32_bf16(aq[0][0], kf0, z0, 0, 0, 0);
            z0 = __builtin_amdgcn_mfma_f32_16x16x32_bf16(aq[0][1], kf1, z0, 0, 0, 0);
            sv[0][nt] = z0;
            f32x4 z1 = {0.f,0.f,0.f,0.f};
            z1 = __builtin_amdgcn_mfma_f32_16x16x32_bf16(aq[1][0], kf0, z1, 0, 0, 0);
            z1 = __builtin_amdgcn_mfma_f32_16x16x32_bf16(aq[1][1], kf1, z1, 0, 0, 0);
            sv[1][nt] = z1;
        }
        __builtin_amdgcn_s_setprio(0);

        // gate + exp + P->LDS per half (Ps region per-wave private);
        // ap frags captured before Ps reuse next iter.
        short8 ap[2][2];
        #pragma unroll
        for (int qh = 0; qh < 2; ++qh) {
            #pragma unroll
            for (int i = 0; i < 4; ++i) {
                const int pr = 4 * fq + i;
                #pragma unroll
                for (int nt = 0; nt < 4; ++nt) {
                    const int idx = i * 4 + nt;
                    const float gv = b2f((u16)(idx < 8 ? g[2 * qh][idx]
                                                       : g[2 * qh + 1][idx - 8]));
                    const float p = FEXP2(sv[qh][nt][i] * gv);
                    l_part[qh][i] += p;
                    const int col = nt * 16 + fr;
                    Ps[w * 1024 + pr * 64 + (((col >> 3) ^ (pr & 7)) << 3) + (col & 7)]
                        = f2b_hu(p);
                }
            }
            ap[qh][0] = *(const short8*)&Ps[w * 1024 + fr * 64 + sega];
            ap[qh][1] = *(const short8*)&Ps[w * 1024 + fr * 64 + segb];
        }

        // O += P . V for both halves; v-frags read once, used twice
        __builtin_amdgcn_s_setprio(1);
        #pragma unroll
        for (int nt = 0; nt < 4; ++nt) {
            short8 vf0 = *(const short8*)&VS[(nt * 16 + fr) * 64 + sega];
            short8 vf1 = *(const short8*)&VS[(nt * 16 + fr) * 64 + segb];
            o[0][nt] = __builtin_amdgcn_mfma_f32_16x16x32_bf16(ap[0][0], vf0, o[0][nt], 0, 0, 0);
            o[0][nt] = __builtin_amdgcn_mfma_f32_16x16x32_bf16(ap[0][1], vf1, o[0][nt], 0, 0, 0);
            o[1][nt] = __builtin_amdgcn_mfma_f32_16x16x32_bf16(ap[1][0], vf0, o[1][nt], 0, 0, 0);
            o[1][nt] = __builtin_amdgcn_mfma_f32_16x16x32_bf16(ap[1][1], vf1, o[1][nt], 0, 0, 0);
        }
        __builtin_amdgcn_s_setprio(0);
    }

    // deferred l reduction + epilogue per half
    #pragma unroll
    for (int qh = 0; qh < 2; ++qh) {
        #pragma unroll
        for (int i = 0; i < 4; ++i) {
            float s = l_part[qh][i];
            s += __shfl_xor(s, 1, 16);
            s += __shfl_xor(s, 2, 16);
            s += __shfl_xor(s, 4, 16);
            s += __shfl_xor(s, 8, 16);
            const float inv = 1.f / s;
            const int n = q0 + qh * 64 + 16 * w + 4 * fq + i;
            const size_t rowoff = ((size_t)b * 1024 + n) * 768 + h * 64;
            #pragma unroll
            for (int nt = 0; nt < 4; ++nt)
                aob[rowoff + nt * 16 + fr] = f2b(o[qh][nt][i] * inv);
        }
    }
}

// ---------------------------------------------------------------------------
// K3: output projection. R9-verified: 128x256 block tile, per-wave 128x64
// (acc[8][4]), depth-3 vmcnt(6) pipeline, grid 192 (24/XCD). fp32 out+bias.
// ---------------------------------------------------------------------------
__global__ __launch_bounds__(256, 2) void proj_gemm(
    const u16* __restrict__ aob, const u16* __restrict__ wb,
    const float* __restrict__ bproj, float* __restrict__ out)
{
    __shared__ u16 As[3][4096];
    __shared__ u16 Bs[3][8192];
    const int t = threadIdx.x, l = t & 63, w = t >> 6;
    const int wc = w * 64;

    const int orig = blockIdx.x;                 // 192 blocks
    const int nid = (orig & 7) * 24 + (orig >> 3);
    const int m0 = (nid / 3) * 128, c0 = (nid % 3) * 256;

    f32x4 acc[8][4];
    #pragma unroll
    for (int i = 0; i < 8; ++i)
        #pragma unroll
        for (int j = 0; j < 4; ++j) { f32x4 z = {0.f,0.f,0.f,0.f}; acc[i][j] = z; }

    const int srow = l >> 2, sseg = l & 3;
    const int gcol = ((sseg ^ ((srow >> 1) & 3)) << 3);
    const u16* aA = aob + (size_t)(m0 + w * 16 + srow) * 768 + gcol;
    const u16* aB = wb + (size_t)(c0 + w * 16 + srow) * 768 + gcol;

    const int fr = l & 15, fq = l >> 4;
    const int fseg = (fq ^ ((fr >> 1) & 3)) << 3;

    auto stage = [&](int bi, int koff) {
        GLL16(aA + koff,                      &As[bi][(w + 0) * 512]);
        GLL16(aA + koff + (size_t)64 * 768,   &As[bi][(w + 4) * 512]);
        GLL16(aB + koff,                      &Bs[bi][(w + 0) * 512]);
        GLL16(aB + koff + (size_t)64 * 768,   &Bs[bi][(w + 4) * 512]);
        GLL16(aB + koff + (size_t)128 * 768,  &Bs[bi][(w + 8) * 512]);
        GLL16(aB + koff + (size_t)192 * 768,  &Bs[bi][(w + 12) * 512]);
    };

    stage(0, 0);
    stage(1, 32);

    int cur = 0;
    for (int kt = 0; kt < 24; ++kt) {
        if (kt < 23) asm volatile("s_waitcnt vmcnt(6)" ::: "memory");
        else         asm volatile("s_waitcnt vmcnt(0)" ::: "memory");
        __builtin_amdgcn_s_barrier();
        if (kt < 22) {
            const int nn = (cur == 0) ? 2 : cur - 1;
            stage(nn, (kt + 2) * 32);
        }
        const u16* A = As[cur];
        const u16* B = Bs[cur];
        short8 af[8], bf[4];
        #pragma unroll
        for (int mt = 0; mt < 8; ++mt)
            af[mt] = *(const short8*)&A[(mt * 16 + fr) * 32 + fseg];
        #pragma unroll
        for (int nt = 0; nt < 4; ++nt)
            bf[nt] = *(const short8*)&B[(wc + nt * 16 + fr) * 32 + fseg];
        #pragma unroll
        for (int mt = 0; mt < 8; ++mt)
            #pragma unroll
            for (int nt = 0; nt < 4; ++nt)
                acc[mt][nt] = __builtin_amdgcn_mfma_f32_16x16x32_bf16(
                    af[mt], bf[nt], acc[mt][nt], 0, 0, 0);
        cur = (cur == 2) ? 0 : cur + 1;
    }

    #pragma unroll
    for (int nt = 0; nt < 4; ++nt) {
        const int c = c0 + wc + nt * 16 + fr;
        const float bias = bproj[c];
        #pragma unroll
        for (int mt = 0; mt < 8; ++mt)
            #pragma unroll
            for (int r = 0; r < 4; ++r) {
                const int m = m0 + mt * 16 + fq * 4 + r;
                out[(size_t)m * 768 + c] = acc[mt][nt][r] + bias;
            }
    }
}

// ---------------------------------------------------------------------------
extern "C" void kernel_launch(void* const* d_in, const int* in_sizes, int n_in,
                              void* d_out, int out_size, void* d_ws, size_t ws_size,
                              hipStream_t stream)
{
    const float* x     = (const float*)d_in[0];
    const float* wqkv  = (const float*)d_in[1];
    const float* wproj = (const float*)d_in[2];
    const float* bproj = (const float*)d_in[3];
    const float* mask  = (const float*)d_in[4];
    float* out = (float*)d_out;

    char* ws = (char*)d_ws;
    u16* gperm  = (u16*)(ws);               // 25,165,824 B
    u16* xb     = (u16*)(ws + 25165824);    // 12,582,912 B
    u16* wqkvb  = (u16*)(ws + 37748736);    //  3,538,944 B
    u16* wprojb = (u16*)(ws + 41287680);    //  1,179,648 B
    u16* qb     = (u16*)(ws + 42467328);    // 12,582,912 B
    u16* kb     = (u16*)(ws + 55050240);    // 12,582,912 B
    u16* vb     = (u16*)(ws + 67633152);    // 12,582,912 B (transposed: B,H,64,N)
    u16* aob    = (u16*)(ws + 80216064);    // 12,582,912 B  (total 92.8 MB)

    prep_all<<<3072 + NXW4 / 256, 256, 0, stream>>>(
        (const float4*)x, (const float4*)wqkv, (const float4*)wproj,
        (ushort4*)xb, (ushort4*)wqkvb, (ushort4*)wprojb,
        (const float4*)mask, gperm);

    qkv_gemm<<<dim3(18, 64), 256, 0, stream>>>(xb, wqkvb, qb, kb, vb);

    flash_attn<<<768, 256, 0, stream>>>(qb, kb, vb, gperm, aob);

    proj_gemm<<<192, 256, 0, stream>>>(aob, wprojb, bproj, out);
}

// Round 9
// 225.893 us; speedup vs baseline: 1.0248x; 1.0211x over previous
//
#include <hip/hip_runtime.h>
#include <math.h>
#include <stdint.h>

typedef unsigned short u16;
typedef __attribute__((ext_vector_type(8))) short short8;
typedef __attribute__((ext_vector_type(4))) float f32x4;

// gate scale: 0.125 (attn scale) * log2(e)  -> p = exp2(s * gate)
#define GATE_SCALE 0.18033688011112042f

#if __has_builtin(__builtin_amdgcn_exp2f)
#define FEXP2(x) __builtin_amdgcn_exp2f(x)
#else
#define FEXP2(x) exp2f(x)
#endif

// fp32 -> bf16 round-to-nearest-even
__device__ __forceinline__ u16 f2b(float f) {
    union { float f; unsigned u; } v; v.f = f;
    unsigned r = v.u + 0x7fffu + ((v.u >> 16) & 1u);
    return (u16)(r >> 16);
}
// fp32 -> bf16 round-half-up
__device__ __forceinline__ u16 f2b_hu(float f) {
    union { float f; unsigned u; } v; v.f = f;
    return (u16)((v.u + 0x8000u) >> 16);
}
__device__ __forceinline__ float b2f(u16 u) {
    union { float f; unsigned u; } v; v.u = ((unsigned)u) << 16; return v.f;
}

// async global->LDS, 16B per lane. lds base wave-uniform; HW adds lane*16.
#define GLL16(gsrc, ldsbase) __builtin_amdgcn_global_load_lds(                    \
    (__attribute__((address_space(1))) void*)(uintptr_t)(gsrc),                   \
    (__attribute__((address_space(3))) void*)(uint32_t)(uintptr_t)(ldsbase),      \
    16, 0, 0)

// ---------------------------------------------------------------------------
// K0: convert x / w_qkv / w_proj to bf16 (xw only; gate prep moved into K1).
// ---------------------------------------------------------------------------
#define NX4  1572864   // 6291456/4
#define NW14 442368
#define NW24 147456
#define NXW4 (NX4 + NW14 + NW24)   // 2162688 -> 8448 blocks

__global__ __launch_bounds__(256) void prep_xw(
    const float4* __restrict__ x, const float4* __restrict__ wq,
    const float4* __restrict__ wp,
    ushort4* __restrict__ xb, ushort4* __restrict__ wqb,
    ushort4* __restrict__ wpb)
{
    size_t i = (size_t)blockIdx.x * 256 + threadIdx.x;
    float4 v; ushort4* dst; size_t j;
    if (i < NX4)            { j = i;               v = x[j];  dst = xb;  }
    else if (i < NX4 + NW14){ j = i - NX4;         v = wq[j]; dst = wqb; }
    else                    { j = i - (NX4 + NW14);v = wp[j]; dst = wpb; }
    ushort4 o; o.x = f2b(v.x); o.y = f2b(v.y); o.z = f2b(v.z); o.w = f2b(v.w);
    dst[j] = o;
}

// ---------------------------------------------------------------------------
// K1: HETEROGENEOUS launch -- QKV GEMM + gate prep in one kernel.
// Blocks [0,1152): R8-measured 2-phase 128x128 GEMM (52.2 us, VGPR 68,
//   LDS 32 KB -> 5 blocks/CU; 1152 blocks = 4.5/CU, all start at t~0).
// Blocks [1152,4224): gate = bf16(GATE_SCALE*sigmoid(mask)) permuted into
//   MFMA C-fragment order (R6-verified layout). These are pure-BW blocks
//   that fill the ~0.5 spare slot/CU during the GEMM (GEMM uses only 18%
//   of HBM BW) and flood all slots once GEMM blocks retire.
// No data dependency between the two paths (gate reads mask only).
// LDS aliased: gate path uses 9 KB of the GEMM's 32 KB.
// q/k written (B,H,N,64); V written TRANSPOSED (B,H,64,N).
// ---------------------------------------------------------------------------
__global__ __launch_bounds__(256) void qkv_gate(
    const u16* __restrict__ xb, const u16* __restrict__ wb,
    u16* __restrict__ qb, u16* __restrict__ kb, u16* __restrict__ vb,
    const float4* __restrict__ mask4, u16* __restrict__ gp)
{
    __shared__ u16 SM[16384];                   // 32 KB
    const int t = threadIdx.x;

    if (blockIdx.x >= 1152) {                   // ---- gate prep path ----
        u16* L = SM;                            // [64][72] view, 9216 B
        const int bid = blockIdx.x - 1152;      // h*256 + qt*16 + kt
        const int kt = bid & 15, qt = (bid >> 4) & 15, h = bid >> 8;

        #pragma unroll
        for (int s = 0; s < 4; ++s) {
            const int idx = t + s * 256;        // 0..1023
            const int row = idx >> 4, c4 = idx & 15;
            float4 v = mask4[(size_t)(h * 1024 + qt * 64 + row) * 256 + kt * 16 + c4];
            L[row * 72 + c4 * 4 + 0] = f2b(GATE_SCALE / (1.f + __expf(-v.x)));
            L[row * 72 + c4 * 4 + 1] = f2b(GATE_SCALE / (1.f + __expf(-v.y)));
            L[row * 72 + c4 * 4 + 2] = f2b(GATE_SCALE / (1.f + __expf(-v.z)));
            L[row * 72 + c4 * 4 + 3] = f2b(GATE_SCALE / (1.f + __expf(-v.w)));
        }
        __syncthreads();

        const int w = t >> 6, l = t & 63;
        const int fq = l >> 4, fr = l & 15;
        union { u16 u[16]; float4 f[2]; } vals;
        #pragma unroll
        for (int i = 0; i < 4; ++i)
            #pragma unroll
            for (int nt = 0; nt < 4; ++nt)
                vals.u[i * 4 + nt] = L[(16 * w + 4 * fq + i) * 72 + nt * 16 + fr];
        float4* dst = (float4*)(gp + (size_t)bid * 4096 + (size_t)t * 16);
        dst[0] = vals.f[0];
        dst[1] = vals.f[1];
        return;
    }

    // ---- GEMM path (R8-measured 2-phase) ----
    u16 (*As)[4096] = (u16(*)[4096])SM;         // 2 x 8 KB
    u16 (*Bs)[4096] = (u16(*)[4096])(SM + 8192);
    const int l = t & 63, w = t >> 6;
    const int wm = (w & 1) * 64, wn = (w >> 1) * 64;

    const int orig = blockIdx.x;                // [0,1152), 144/XCD
    const int nid = (orig & 7) * 144 + (orig >> 3);
    const int m0 = (nid / 18) * 128, c0 = (nid % 18) * 128;

    f32x4 acc[4][4];
    #pragma unroll
    for (int i = 0; i < 4; ++i)
        #pragma unroll
        for (int j = 0; j < 4; ++j) { f32x4 z = {0.f,0.f,0.f,0.f}; acc[i][j] = z; }

    const int srow = l >> 2, sseg = l & 3;
    const int gcol = ((sseg ^ ((srow >> 1) & 3)) << 3);
    const u16* a0 = xb + (size_t)(m0 + w * 16 + srow) * 768 + gcol;
    const u16* a1 = a0 + (size_t)64 * 768;
    const u16* b0p = wb + (size_t)(c0 + w * 16 + srow) * 768 + gcol;
    const u16* b1p = b0p + (size_t)64 * 768;
    const int wofs = w * 512;

    const int fr = l & 15, fq = l >> 4;
    const int fseg = (fq ^ ((fr >> 1) & 3)) << 3;

    auto stage = [&](int bi, int koff) {
        GLL16(a0 + koff, &As[bi][wofs]);
        GLL16(a1 + koff, &As[bi][2048 + wofs]);
        GLL16(b0p + koff, &Bs[bi][wofs]);
        GLL16(b1p + koff, &Bs[bi][2048 + wofs]);
    };

    stage(0, 0);

    for (int kt = 0; kt < 24; ++kt) {
        asm volatile("s_waitcnt vmcnt(0)" ::: "memory");
        __builtin_amdgcn_s_barrier();
        if (kt < 23) stage((kt + 1) & 1, (kt + 1) * 32);
        const u16* A = As[kt & 1];
        const u16* B = Bs[kt & 1];
        short8 af[4], bf[4];
        #pragma unroll
        for (int mt = 0; mt < 4; ++mt)
            af[mt] = *(const short8*)&A[(wm + mt * 16 + fr) * 32 + fseg];
        #pragma unroll
        for (int nt = 0; nt < 4; ++nt)
            bf[nt] = *(const short8*)&B[(wn + nt * 16 + fr) * 32 + fseg];
        #pragma unroll
        for (int mt = 0; mt < 4; ++mt)
            #pragma unroll
            for (int nt = 0; nt < 4; ++nt)
                acc[mt][nt] = __builtin_amdgcn_mfma_f32_16x16x32_bf16(
                    af[mt], bf[nt], acc[mt][nt], 0, 0, 0);
    }

    const int b = m0 >> 10;
    const int n0 = m0 & 1023;
    #pragma unroll
    for (int nt = 0; nt < 4; ++nt) {
        const int c = c0 + wn + nt * 16 + fr;
        const int which = c / 768;
        const int rem = c - which * 768;
        const int h = rem >> 6, d = rem & 63;
        if (which < 2) {
            u16* dst = ((which == 0) ? qb : kb)
                       + ((size_t)(b * 12 + h) * 1024) * 64 + d;
            #pragma unroll
            for (int mt = 0; mt < 4; ++mt)
                #pragma unroll
                for (int r = 0; r < 4; ++r) {
                    const int n = n0 + wm + mt * 16 + fq * 4 + r;
                    dst[(size_t)n * 64] = f2b(acc[mt][nt][r]);
                }
        } else {
            u16* dst = vb + ((size_t)(b * 12 + h) * 64 + d) * 1024
                          + n0 + wm + fq * 4;
            #pragma unroll
            for (int mt = 0; mt < 4; ++mt) {
                ushort4 pk;
                pk.x = f2b(acc[mt][nt][0]); pk.y = f2b(acc[mt][nt][1]);
                pk.z = f2b(acc[mt][nt][2]); pk.w = f2b(acc[mt][nt][3]);
                *(ushort4*)(dst + mt * 16) = pk;
            }
        }
    }
}

// ---------------------------------------------------------------------------
// K2: flash attention. R6-verified: normal QK order, scalar P writes, Q
// direct to regs, K/V double-buffer with one raw s_barrier + counted
// vmcnt(4), K/V-colocating XCD remap, setprio around MFMA clusters.
// ---------------------------------------------------------------------------
__global__ __launch_bounds__(256, 3) void flash_attn(
    const u16* __restrict__ qb, const u16* __restrict__ kb,
    const u16* __restrict__ vt, const u16* __restrict__ gperm,
    u16* __restrict__ aob)
{
    __shared__ u16 Ks[2][4096], Vts[2][4096], Ps[4096];
    const int t = threadIdx.x, l = t & 63, w = t >> 6;
    const int bid = blockIdx.x;
    // K/V-colocating remap: all 8 qtb-siblings of one (b,h) on one XCD
    const int xcd = bid & 7, jj = bid >> 3;
    const int bh = (jj % 12) * 8 + xcd;
    const int qtb = jj / 12;
    const int h = bh % 12, b = bh / 12;
    const int q0 = qtb * 128;

    const u16* hq = qb + (size_t)bh * 65536;
    const u16* hk = kb + (size_t)bh * 65536;
    const u16* hv = vt + (size_t)bh * 65536;
    // gate tiles (h, 2*qtb + qh, kt); qh=1 at +16 tiles = +65536 u16
    const u16* hgb = gperm + ((size_t)h * 256 + qtb * 32) * 4096 + (w * 64 + l) * 16;

    const int sr = l >> 3, ss = l & 7;
    const int sg = ((ss ^ (sr & 7)) << 3);
    const int j0 = w * 2, j1 = j0 + 1;

    const int fq = l >> 4, fr = l & 15;
    const int sega = ((fq ^ (fr & 7)) << 3);
    const int segb = (((4 + fq) ^ (fr & 7)) << 3);

    // Q A-frags (kt-invariant) direct from global
    short8 aq[2][2];
    #pragma unroll
    for (int qh = 0; qh < 2; ++qh) {
        const u16* qrow = hq + (size_t)(q0 + qh * 64 + 16 * w + fr) * 64;
        aq[qh][0] = *(const short8*)(qrow + fq * 8);
        aq[qh][1] = *(const short8*)(qrow + 32 + fq * 8);
    }

    // stage kt=0 K/V into buf 0
    GLL16(hk + (size_t)(j0 * 8 + sr) * 64 + sg, &Ks[0][j0 * 512]);
    GLL16(hk + (size_t)(j1 * 8 + sr) * 64 + sg, &Ks[0][j1 * 512]);
    GLL16(hv + (size_t)(j0 * 8 + sr) * 1024 + sg, &Vts[0][j0 * 512]);
    GLL16(hv + (size_t)(j1 * 8 + sr) * 1024 + sg, &Vts[0][j1 * 512]);
    __builtin_amdgcn_sched_barrier(0);

    // gate prefetch for kt=0 (both halves)
    short8 gn[4];
    gn[0] = *(const short8*)(hgb);
    gn[1] = *(const short8*)(hgb + 8);
    gn[2] = *(const short8*)(hgb + 65536);
    gn[3] = *(const short8*)(hgb + 65536 + 8);

    float l_part[2][4] = {{0.f,0.f,0.f,0.f},{0.f,0.f,0.f,0.f}};
    f32x4 o[2][4];
    #pragma unroll
    for (int qh = 0; qh < 2; ++qh)
        #pragma unroll
        for (int nt = 0; nt < 4; ++nt) { f32x4 z = {0.f,0.f,0.f,0.f}; o[qh][nt] = z; }

    for (int kt = 0; kt < 16; ++kt) {
        // own buf[kt&1] GLL16s done (4 gate loads may stay outstanding)
        asm volatile("s_waitcnt vmcnt(4)" ::: "memory");
        __builtin_amdgcn_s_barrier();

        if (kt < 15) {                          // stage kt+1 into buf^1
            const size_t ko = (size_t)(kt + 1) * 64;
            u16* kd = &Ks[(kt + 1) & 1][0];
            u16* vd = &Vts[(kt + 1) & 1][0];
            GLL16(hk + (ko + j0 * 8 + sr) * 64 + sg, kd + j0 * 512);
            GLL16(hk + (ko + j1 * 8 + sr) * 64 + sg, kd + j1 * 512);
            GLL16(hv + (size_t)(j0 * 8 + sr) * 1024 + ko + sg, vd + j0 * 512);
            GLL16(hv + (size_t)(j1 * 8 + sr) * 1024 + ko + sg, vd + j1 * 512);
            __builtin_amdgcn_sched_barrier(0);  // keep GLL16s older than gate loads
        }

        short8 g[4];
        #pragma unroll
        for (int s = 0; s < 4; ++s) g[s] = gn[s];
        if (kt < 15) {                          // gate register prefetch, 1 ahead
            const size_t go = (size_t)(kt + 1) * 4096;
            gn[0] = *(const short8*)(hgb + go);
            gn[1] = *(const short8*)(hgb + go + 8);
            gn[2] = *(const short8*)(hgb + 65536 + go);
            gn[3] = *(const short8*)(hgb + 65536 + go + 8);
        }

        const u16* KS = &Ks[kt & 1][0];
        const u16* VS = &Vts[kt & 1][0];

        // S = Q . K^T for both halves; k-frags read once, used twice
        f32x4 sv[2][4];
        __builtin_amdgcn_s_setprio(1);
        #pragma unroll
        for (int nt = 0; nt < 4; ++nt) {
            short8 kf0 = *(const short8*)&KS[(nt * 16 + fr) * 64 + sega];
            short8 kf1 = *(const short8*)&KS[(nt * 16 + fr) * 64 + segb];
            f32x4 z0 = {0.f,0.f,0.f,0.f};
            z0 = __builtin_amdgcn_mfma_f32_16x16x32_bf16(aq[0][0], kf0, z0, 0, 0, 0);
            z0 = __builtin_amdgcn_mfma_f32_16x16x32_bf16(aq[0][1], kf1, z0, 0, 0, 0);
            sv[0][nt] = z0;
            f32x4 z1 = {0.f,0.f,0.f,0.f};
            z1 = __builtin_amdgcn_mfma_f32_16x16x32_bf16(aq[1][0], kf0, z1, 0, 0, 0);
            z1 = __builtin_amdgcn_mfma_f32_16x16x32_bf16(aq[1][1], kf1, z1, 0, 0, 0);
            sv[1][nt] = z1;
        }
        __builtin_amdgcn_s_setprio(0);

        // gate + exp + P->LDS per half (Ps region per-wave private);
        // ap frags captured before Ps reuse next iter.
        short8 ap[2][2];
        #pragma unroll
        for (int qh = 0; qh < 2; ++qh) {
            #pragma unroll
            for (int i = 0; i < 4; ++i) {
                const int pr = 4 * fq + i;
                #pragma unroll
                for (int nt = 0; nt < 4; ++nt) {
                    const int idx = i * 4 + nt;
                    const float gv = b2f((u16)(idx < 8 ? g[2 * qh][idx]
                                                       : g[2 * qh + 1][idx - 8]));
                    const float p = FEXP2(sv[qh][nt][i] * gv);
                    l_part[qh][i] += p;
                    const int col = nt * 16 + fr;
                    Ps[w * 1024 + pr * 64 + (((col >> 3) ^ (pr & 7)) << 3) + (col & 7)]
                        = f2b_hu(p);
                }
            }
            ap[qh][0] = *(const short8*)&Ps[w * 1024 + fr * 64 + sega];
            ap[qh][1] = *(const short8*)&Ps[w * 1024 + fr * 64 + segb];
        }

        // O += P . V for both halves; v-frags read once, used twice
        __builtin_amdgcn_s_setprio(1);
        #pragma unroll
        for (int nt = 0; nt < 4; ++nt) {
            short8 vf0 = *(const short8*)&VS[(nt * 16 + fr) * 64 + sega];
            short8 vf1 = *(const short8*)&VS[(nt * 16 + fr) * 64 + segb];
            o[0][nt] = __builtin_amdgcn_mfma_f32_16x16x32_bf16(ap[0][0], vf0, o[0][nt], 0, 0, 0);
            o[0][nt] = __builtin_amdgcn_mfma_f32_16x16x32_bf16(ap[0][1], vf1, o[0][nt], 0, 0, 0);
            o[1][nt] = __builtin_amdgcn_mfma_f32_16x16x32_bf16(ap[1][0], vf0, o[1][nt], 0, 0, 0);
            o[1][nt] = __builtin_amdgcn_mfma_f32_16x16x32_bf16(ap[1][1], vf1, o[1][nt], 0, 0, 0);
        }
        __builtin_amdgcn_s_setprio(0);
    }

    // deferred l reduction + epilogue per half
    #pragma unroll
    for (int qh = 0; qh < 2; ++qh) {
        #pragma unroll
        for (int i = 0; i < 4; ++i) {
            float s = l_part[qh][i];
            s += __shfl_xor(s, 1, 16);
            s += __shfl_xor(s, 2, 16);
            s += __shfl_xor(s, 4, 16);
            s += __shfl_xor(s, 8, 16);
            const float inv = 1.f / s;
            const int n = q0 + qh * 64 + 16 * w + 4 * fq + i;
            const size_t rowoff = ((size_t)b * 1024 + n) * 768 + h * 64;
            #pragma unroll
            for (int nt = 0; nt < 4; ++nt)
                aob[rowoff + nt * 16 + fr] = f2b(o[qh][nt][i] * inv);
        }
    }
}

// ---------------------------------------------------------------------------
// K3: output projection. R9-verified: 128x256 block tile, per-wave 128x64
// (acc[8][4]), depth-3 vmcnt(6) pipeline, grid 192 (24/XCD). fp32 out+bias.
// ---------------------------------------------------------------------------
__global__ __launch_bounds__(256, 2) void proj_gemm(
    const u16* __restrict__ aob, const u16* __restrict__ wb,
    const float* __restrict__ bproj, float* __restrict__ out)
{
    __shared__ u16 As[3][4096];
    __shared__ u16 Bs[3][8192];
    const int t = threadIdx.x, l = t & 63, w = t >> 6;
    const int wc = w * 64;

    const int orig = blockIdx.x;                 // 192 blocks
    const int nid = (orig & 7) * 24 + (orig >> 3);
    const int m0 = (nid / 3) * 128, c0 = (nid % 3) * 256;

    f32x4 acc[8][4];
    #pragma unroll
    for (int i = 0; i < 8; ++i)
        #pragma unroll
        for (int j = 0; j < 4; ++j) { f32x4 z = {0.f,0.f,0.f,0.f}; acc[i][j] = z; }

    const int srow = l >> 2, sseg = l & 3;
    const int gcol = ((sseg ^ ((srow >> 1) & 3)) << 3);
    const u16* aA = aob + (size_t)(m0 + w * 16 + srow) * 768 + gcol;
    const u16* aB = wb + (size_t)(c0 + w * 16 + srow) * 768 + gcol;

    const int fr = l & 15, fq = l >> 4;
    const int fseg = (fq ^ ((fr >> 1) & 3)) << 3;

    auto stage = [&](int bi, int koff) {
        GLL16(aA + koff,                      &As[bi][(w + 0) * 512]);
        GLL16(aA + koff + (size_t)64 * 768,   &As[bi][(w + 4) * 512]);
        GLL16(aB + koff,                      &Bs[bi][(w + 0) * 512]);
        GLL16(aB + koff + (size_t)64 * 768,   &Bs[bi][(w + 4) * 512]);
        GLL16(aB + koff + (size_t)128 * 768,  &Bs[bi][(w + 8) * 512]);
        GLL16(aB + koff + (size_t)192 * 768,  &Bs[bi][(w + 12) * 512]);
    };

    stage(0, 0);
    stage(1, 32);

    int cur = 0;
    for (int kt = 0; kt < 24; ++kt) {
        if (kt < 23) asm volatile("s_waitcnt vmcnt(6)" ::: "memory");
        else         asm volatile("s_waitcnt vmcnt(0)" ::: "memory");
        __builtin_amdgcn_s_barrier();
        if (kt < 22) {
            const int nn = (cur == 0) ? 2 : cur - 1;
            stage(nn, (kt + 2) * 32);
        }
        const u16* A = As[cur];
        const u16* B = Bs[cur];
        short8 af[8], bf[4];
        #pragma unroll
        for (int mt = 0; mt < 8; ++mt)
            af[mt] = *(const short8*)&A[(mt * 16 + fr) * 32 + fseg];
        #pragma unroll
        for (int nt = 0; nt < 4; ++nt)
            bf[nt] = *(const short8*)&B[(wc + nt * 16 + fr) * 32 + fseg];
        #pragma unroll
        for (int mt = 0; mt < 8; ++mt)
            #pragma unroll
            for (int nt = 0; nt < 4; ++nt)
                acc[mt][nt] = __builtin_amdgcn_mfma_f32_16x16x32_bf16(
                    af[mt], bf[nt], acc[mt][nt], 0, 0, 0);
        cur = (cur == 2) ? 0 : cur + 1;
    }

    #pragma unroll
    for (int nt = 0; nt < 4; ++nt) {
        const int c = c0 + wc + nt * 16 + fr;
        const float bias = bproj[c];
        #pragma unroll
        for (int mt = 0; mt < 8; ++mt)
            #pragma unroll
            for (int r = 0; r < 4; ++r) {
                const int m = m0 + mt * 16 + fq * 4 + r;
                out[(size_t)m * 768 + c] = acc[mt][nt][r] + bias;
            }
    }
}

// ---------------------------------------------------------------------------
extern "C" void kernel_launch(void* const* d_in, const int* in_sizes, int n_in,
                              void* d_out, int out_size, void* d_ws, size_t ws_size,
                              hipStream_t stream)
{
    const float* x     = (const float*)d_in[0];
    const float* wqkv  = (const float*)d_in[1];
    const float* wproj = (const float*)d_in[2];
    const float* bproj = (const float*)d_in[3];
    const float* mask  = (const float*)d_in[4];
    float* out = (float*)d_out;

    char* ws = (char*)d_ws;
    u16* gperm  = (u16*)(ws);               // 25,165,824 B
    u16* xb     = (u16*)(ws + 25165824);    // 12,582,912 B
    u16* wqkvb  = (u16*)(ws + 37748736);    //  3,538,944 B
    u16* wprojb = (u16*)(ws + 41287680);    //  1,179,648 B
    u16* qb     = (u16*)(ws + 42467328);    // 12,582,912 B
    u16* kb     = (u16*)(ws + 55050240);    // 12,582,912 B
    u16* vb     = (u16*)(ws + 67633152);    // 12,582,912 B (transposed: B,H,64,N)
    u16* aob    = (u16*)(ws + 80216064);    // 12,582,912 B  (total 92.8 MB)

    prep_xw<<<NXW4 / 256, 256, 0, stream>>>(
        (const float4*)x, (const float4*)wqkv, (const float4*)wproj,
        (ushort4*)xb, (ushort4*)wqkvb, (ushort4*)wprojb);

    qkv_gate<<<4224, 256, 0, stream>>>(
        xb, wqkvb, qb, kb, vb, (const float4*)mask, gperm);

    flash_attn<<<768, 256, 0, stream>>>(qb, kb, vb, gperm, aob);

    proj_gemm<<<192, 256, 0, stream>>>(aob, wprojb, bproj, out);
}